// Round 18
// baseline (87.213 us; speedup 1.0000x reference)
//
#include <hip/hip_runtime.h>

// Fused capsule conv + dynamic routing: 2 pixels/block, MFMA, XCD-ownership.
// x:      [8, 32, 8, 32, 32] f32   (bs, ci, ni, hi, wi)
// conv_w: [256, 8, 3, 3]     f32   (co*no, ni, kh, kw)
// bias:   [32, 8, 1, 1]      f32
// out:    [8, 32, 8, 32, 32] f32   (bs, co, no, ho, wo)
//
// R15 (73.15us, proven: WRITE 12MB, no spill) + ONE change (R16 post-mortem:
// bundling permlane16_swap + reorder spilled ~33MB scratch; unbundled here):
//  - dist butterfly level-REORDER xor1->xor2->xor4: levels 1,2 quad-local
//    (DPP, VALU); ONE scalar shfl_xor4 per site (was 4 DS: 2x shfl2(,4)).
//    Slot mapping unchanged: slot=(b4,b2,b1)=no. -48 DS ops/thread.
//  - permlane16_swap NOT used (pair-returning builtin at 24 serial-chain
//    sites was the likely pressure source); xor16 stays on DS as in R15.
// Register live-set otherwise unchanged (64 VGPR + 64 AGPR = 128 cap).

typedef __attribute__((ext_vector_type(8))) short short8;
typedef __attribute__((ext_vector_type(4))) float f32x4;
typedef __attribute__((ext_vector_type(2))) float f32x2;

#define LSTR 104   // A row stride in ushorts (208 B)
#define KP   96    // packed K per col: [hi 72][zero 24]
#define RSTR 36    // routeT row stride (f32)
#define LGS  37    // logits row stride (f32): bank (5*ci+j), ~2-way

__device__ __forceinline__ ushort f2bf_rne(float f) {
    unsigned u = __float_as_uint(f);
    return (ushort)((u + 0x7fffu + ((u >> 16) & 1u)) >> 16);
}
__device__ __forceinline__ f32x2 lo2(f32x4 v) { f32x2 r; r[0] = v[0]; r[1] = v[1]; return r; }
__device__ __forceinline__ f32x2 hi2(f32x4 v) { f32x2 r; r[0] = v[2]; r[1] = v[3]; return r; }
__device__ __forceinline__ f32x2 shfl2(f32x2 v, int m) {
    f32x2 r; r[0] = __shfl_xor(v[0], m); r[1] = __shfl_xor(v[1], m); return r;
}
// quad_perm DPP: lane^1 = 0xB1, lane^2 = 0x4E. VALU pipe, not DS.
__device__ __forceinline__ float dpp_xor1(float x) {
    return __int_as_float(__builtin_amdgcn_update_dpp(
        0, __float_as_int(x), 0xB1, 0xf, 0xf, true));
}
__device__ __forceinline__ float dpp_xor2(float x) {
    return __int_as_float(__builtin_amdgcn_update_dpp(
        0, __float_as_int(x), 0x4E, 0xf, 0xf, true));
}
// p + shfl_xor(p,32) via v_permlane32_swap (VALU, proven R14).
__device__ __forceinline__ float addswap32(float p) {
    unsigned u = __float_as_uint(p);
    auto r = __builtin_amdgcn_permlane32_swap(u, u, false, false);
    return __uint_as_float(r[0]) + __uint_as_float(r[1]);
}
// butterfly level-1 (slot bit0): collapse a f32x2 via quad DPP.
__device__ __forceinline__ float red1(f32x2 v, bool b1) {
    float keep = b1 ? v[1] : v[0];
    float send = b1 ? v[0] : v[1];
    return keep + dpp_xor1(send);
}

__global__ void prep_w(const float* __restrict__ cw, ushort* __restrict__ wp) {
    int e = blockIdx.x * 256 + threadIdx.x;   // [col=256][k=96]
    int col = e / KP, k = e - col * KP;
    float v = (k < 72) ? cw[col * 72 + k] : 0.0f;
    wp[e] = f2bf_rne(v);
}

__global__ __launch_bounds__(256, 4)
void caps_mfma2(const float* __restrict__ x,
                const ushort* __restrict__ wp,
                const float* __restrict__ bias,
                float* __restrict__ out)
{
    __shared__ ushort A[64 * LSTR];        // 13,312 B
    __shared__ float  logits[2][32 * LGS]; //  9,472 B  [px][ci][co] stride 37
    __shared__ float  routeT[2][32 * RSTR];//  9,216 B  [px][co][ci]

    const int t    = threadIdx.x;
    const int braw = blockIdx.x;                 // grid = 4096
    // XCD-ownership swizzle (bijective, 4096 = 8*512): XCD k owns batch k.
    const int bid = ((braw & 7) << 9) | (braw >> 3);
    const int b   = bid >> 9;
    const int q   = bid & 511;
    const int hw0 = q << 1;                      // even; pair = (hw0, hw0+1)
    const int h   = hw0 >> 5;
    const int w0  = hw0 & 31;                    // even, <= 30

    // ---- stage A rows: thread t <-> (row = t>>2 = px*32+ci, ni in {2qn,2qn+1})
    {
        const int row = t >> 2, qn = t & 3;
        const int px = row >> 5, ci = row & 31;
        const int wpx = w0 + px;
        const float* xb0 = x + (((size_t)((b * 32 + ci) * 8 + qn * 2)) << 10);
        const float* xb1 = xb0 + 1024;
        ushort hbuf[18];
        #pragma unroll
        for (int kh = 0; kh < 3; ++kh) {
            int hy = h + kh - 1;
            bool vh = (unsigned)hy < 32u;
            int base = hy << 5;
            #pragma unroll
            for (int c = 0; c < 3; ++c) {
                int wx = wpx + c - 1;
                bool ok = vh && ((unsigned)wx < 32u);
                float f0 = ok ? xb0[base + wx] : 0.0f;
                float f1 = ok ? xb1[base + wx] : 0.0f;
                hbuf[kh * 3 + c]     = f2bf_rne(f0);
                hbuf[9 + kh * 3 + c] = f2bf_rne(f1);
            }
        }
        // packed uint writes: shorts [row*LSTR + qn*18, +18)
        uint* Au = reinterpret_cast<uint*>(A);
        int hbase = row * (LSTR / 2) + qn * 9;
        #pragma unroll
        for (int i = 0; i < 9; ++i)
            Au[hbase + i] = (unsigned)hbuf[2 * i] | ((unsigned)hbuf[2 * i + 1] << 16);
        // zero K-pad shorts 72..103 (16 uints/row, 4 threads -> 4 each)
        int pbase = row * (LSTR / 2) + 36 + qn * 4;
        Au[pbase + 0] = 0u; Au[pbase + 1] = 0u;
        Au[pbase + 2] = 0u; Au[pbase + 3] = 0u;
    }
    __syncthreads();                     // barrier 1 (staging -> GEMM)

    const int lane = t & 63, wv = t >> 6;
    const int lc = lane & 15, grp = lane >> 4;
    const int no = lane & 7;
    const int par = (lane >> 3) & 1;

    // ---- GEMM: D[64 rows][256 cols], rows = px*32+ci. 3 k-steps of 32.
    f32x4 acc[4][4];
    #pragma unroll
    for (int mt = 0; mt < 4; ++mt)
        #pragma unroll
        for (int j = 0; j < 4; ++j) acc[mt][j] = (f32x4){0.f, 0.f, 0.f, 0.f};

    #pragma unroll
    for (int ks = 0; ks < 3; ++ks) {
        short8 bq[4];
        #pragma unroll
        for (int j = 0; j < 4; ++j) {
            int col = wv * 64 + j * 16 + lc;
            bq[j] = *reinterpret_cast<const short8*>(wp + col * KP + ks * 32 + grp * 8);
        }
        #pragma unroll
        for (int mt = 0; mt < 4; ++mt) {
            short8 af = *reinterpret_cast<const short8*>(A + (mt * 16 + lc) * LSTR + ks * 32 + grp * 8);
            #pragma unroll
            for (int j = 0; j < 4; ++j)
                acc[mt][j] = __builtin_amdgcn_mfma_f32_16x16x32_bf16(af, bq[j], acc[mt][j], 0, 0, 0);
        }
    }
    // no barrier: A is read-only from here; routing uses separate buffers

    float bj[4];
    #pragma unroll
    for (int j = 0; j < 4; ++j) bj[j] = bias[wv * 64 + j * 16 + lc];

    const int ci_s = t >> 3, j_s = t & 7;
    const int ci_w = ((no >> 2) << 4) + (grp << 2) + (no & 3);   // dist write row
    const bool b4 = (no & 4) != 0, b2 = (no & 2) != 0, b1 = (no & 1) != 0;
    float act_[2][4];

    // ================= iteration 0: route = 1/32 exactly =================
    #pragma unroll
    for (int px = 0; px < 2; ++px) {
        #pragma unroll
        for (int j = 0; j < 4; ++j) {
            f32x4 s4 = acc[px * 2][j] + acc[px * 2 + 1][j];   // 2 pk_add
            f32x2 s2v = lo2(s4) + hi2(s4);                     // 1 pk_add
            float p = s2v[0] + s2v[1];
            p += __shfl_xor(p, 16);             // DS (as R15)
            p = addswap32(p);                   // VALU (permlane32_swap)
            p = p * 0.03125f + bj[j];
            float s2 = p * p;
            s2 += dpp_xor1(s2);                 // VALU DPP
            s2 += dpp_xor2(s2);                 // VALU DPP
            s2 += __shfl_xor(s2, 4);            // cross-quad: DS
            act_[px][j] = p * __builtin_amdgcn_sqrtf(s2)
                            * __builtin_amdgcn_rcpf(1.0f + s2);
        }
    }
    // distances -> logits (pure write of all 1024 (ci,co) per pixel)
    // butterfly reordered xor1->xor2->xor4: only ONE DS op per site.
    #pragma unroll
    for (int px = 0; px < 2; ++px) {
        float* lg = logits[px];
        #pragma unroll
        for (int j = 0; j < 4; ++j) {
            float a = act_[px][j];
            f32x2 a2; a2[0] = a; a2[1] = a;
            f32x2 d01 = lo2(acc[px * 2][j]) * a2;       // pk_mul x4
            f32x2 d23 = hi2(acc[px * 2][j]) * a2;
            f32x2 d45 = lo2(acc[px * 2 + 1][j]) * a2;
            f32x2 d67 = hi2(acc[px * 2 + 1][j]) * a2;
            float e0 = red1(d01, b1), e1 = red1(d23, b1);   // level 1: DPP
            float e2 = red1(d45, b1), e3 = red1(d67, b1);
            float f0 = (b2 ? e1 : e0) + dpp_xor2(b2 ? e0 : e1);  // level 2: DPP
            float f1 = (b2 ? e3 : e2) + dpp_xor2(b2 ? e2 : e3);
            float r  = (b4 ? f1 : f0) + __shfl_xor(b4 ? f0 : f1, 4);  // level 3: DS
            int co = (wv << 3) + 2 * j + par;
            lg[ci_w * LGS + co] = r;
        }
    }
    __syncthreads();                     // barrier 2 (dist0 -> softmax1)

    // ================= iterations 1 and 2 =================
    for (int it = 1; it <= 2; ++it) {
        // (a) softmax over co per pixel (no max-subtract: |logits| small);
        //     store transposed routeT[co][ci]
        #pragma unroll
        for (int px = 0; px < 2; ++px) {
            const float* lg = logits[px];
            float* rt = routeT[px];
            float e0 = __expf(lg[ci_s * LGS + j_s]);
            float e1 = __expf(lg[ci_s * LGS + j_s + 8]);
            float e2 = __expf(lg[ci_s * LGS + j_s + 16]);
            float e3 = __expf(lg[ci_s * LGS + j_s + 24]);
            float s = e0 + e1 + e2 + e3;
            s += dpp_xor1(s);               // VALU DPP
            s += dpp_xor2(s);               // VALU DPP
            s += __shfl_xor(s, 4);          // cross-quad: DS
            float inv = __builtin_amdgcn_rcpf(s);
            rt[(j_s)      * RSTR + ci_s] = e0 * inv;
            rt[(j_s + 8)  * RSTR + ci_s] = e1 * inv;
            rt[(j_s + 16) * RSTR + ci_s] = e2 * inv;
            rt[(j_s + 24) * RSTR + ci_s] = e3 * inv;
        }
        __syncthreads();                 // barrier 3 / 5 (routeT -> preact)

        // (b) preactivate (packed dot, ci-reduce xor16 + permlane32) + squash
        #pragma unroll
        for (int px = 0; px < 2; ++px) {
            const float* rt = routeT[px];
            #pragma unroll
            for (int j = 0; j < 4; ++j) {
                int co = (wv << 3) + 2 * j + par;
                f32x4 r0 = *reinterpret_cast<const f32x4*>(rt + co * RSTR + grp * 4);
                f32x4 r1 = *reinterpret_cast<const f32x4*>(rt + co * RSTR + 16 + grp * 4);
                f32x2 pp = lo2(r0) * lo2(acc[px * 2][j]);          // pk_mul
                pp = hi2(r0) * hi2(acc[px * 2][j]) + pp;           // pk_fma
                pp = lo2(r1) * lo2(acc[px * 2 + 1][j]) + pp;
                pp = hi2(r1) * hi2(acc[px * 2 + 1][j]) + pp;
                float p = pp[0] + pp[1];
                p += __shfl_xor(p, 16);         // DS (as R15)
                p = addswap32(p);               // VALU swap, not DS
                p += bj[j];
                float s2 = p * p;
                s2 += dpp_xor1(s2);             // VALU DPP
                s2 += dpp_xor2(s2);             // VALU DPP
                s2 += __shfl_xor(s2, 4);        // cross-quad: DS
                act_[px][j] = p * __builtin_amdgcn_sqrtf(s2)
                                * __builtin_amdgcn_rcpf(1.0f + s2);
            }
        }
        if (it == 2) break;

        // (c) distances += (reordered butterfly), accumulate into logits
        #pragma unroll
        for (int px = 0; px < 2; ++px) {
            float* lg = logits[px];
            #pragma unroll
            for (int j = 0; j < 4; ++j) {
                float a = act_[px][j];
                f32x2 a2; a2[0] = a; a2[1] = a;
                f32x2 d01 = lo2(acc[px * 2][j]) * a2;
                f32x2 d23 = hi2(acc[px * 2][j]) * a2;
                f32x2 d45 = lo2(acc[px * 2 + 1][j]) * a2;
                f32x2 d67 = hi2(acc[px * 2 + 1][j]) * a2;
                float e0 = red1(d01, b1), e1 = red1(d23, b1);
                float e2 = red1(d45, b1), e3 = red1(d67, b1);
                float f0 = (b2 ? e1 : e0) + dpp_xor2(b2 ? e0 : e1);
                float f1 = (b2 ? e3 : e2) + dpp_xor2(b2 ? e2 : e3);
                float r  = (b4 ? f1 : f0) + __shfl_xor(b4 ? f0 : f1, 4);
                int co = (wv << 3) + 2 * j + par;
                lg[ci_w * LGS + co] += r;
            }
        }
        __syncthreads();                 // barrier 4 (dist1 -> softmax2)
    }

    // ---- output: grp 0 writes the wave's 64 cols, both pixels as float2
    if (grp == 0) {
        #pragma unroll
        for (int j = 0; j < 4; ++j) {
            int col = wv * 64 + j * 16 + lc;
            float2 v; v.x = act_[0][j]; v.y = act_[1][j];
            *reinterpret_cast<float2*>(out + ((((size_t)b << 8) + col) << 10) + hw0) = v;
        }
    }
}

extern "C" void kernel_launch(void* const* d_in, const int* in_sizes, int n_in,
                              void* d_out, int out_size, void* d_ws, size_t ws_size,
                              hipStream_t stream) {
    const float* x    = (const float*)d_in[0];
    const float* cw   = (const float*)d_in[1];
    const float* bias = (const float*)d_in[2];
    float* out = (float*)d_out;
    ushort* wp = (ushort*)d_ws;           // 256*96*2 = 49,152 B
    (void)in_sizes; (void)n_in; (void)out_size; (void)ws_size;
    prep_w<<<96, 256, 0, stream>>>(cw, wp);
    caps_mfma2<<<4096, 256, 0, stream>>>(x, wp, bias, out);
}

// Round 19
// 72.987 us; speedup vs baseline: 1.1949x; 1.1949x over previous
//
#include <hip/hip_runtime.h>

// Fused capsule conv + dynamic routing: 2 pixels/block, MFMA, XCD-ownership.
// x:      [8, 32, 8, 32, 32] f32   (bs, ci, ni, hi, wi)
// conv_w: [256, 8, 3, 3]     f32   (co*no, ni, kh, kw)
// bias:   [32, 8, 1, 1]      f32
// out:    [8, 32, 8, 32, 32] f32   (bs, co, no, ho, wo)
//
// EXACT R15 restore (73.15us, best proven). R16 (permlane16_swap+reorder)
// and R17 (reorder alone) both spilled ~33-75MB scratch: this kernel sits
// at EXACTLY the 128-unified-reg cap (64 VGPR + 64 AGPR acc @ LB(256,4));
// any liveness-increasing transform tips the allocator into spilling the
// accumulators. Admissible changes are exhausted -> lock in the optimum.
// Techniques: pixel-pair ILP-2, single-term bf16 MFMA GEMM (K=96, 3
// k-steps, B-frags from L2-resident global), XCD-ownership swizzle,
// 5 barriers, no-max-sub softmax, pk-f32 routing math, DPP quad reduces,
// permlane32_swap ci-reduce, stride-37 logits (bank-spread), builtin
// sqrt/rcp, float2 stores.

typedef __attribute__((ext_vector_type(8))) short short8;
typedef __attribute__((ext_vector_type(4))) float f32x4;
typedef __attribute__((ext_vector_type(2))) float f32x2;

#define LSTR 104   // A row stride in ushorts (208 B)
#define KP   96    // packed K per col: [hi 72][zero 24]
#define RSTR 36    // routeT row stride (f32)
#define LGS  37    // logits row stride (f32): bank (5*ci+j), ~2-way

__device__ __forceinline__ ushort f2bf_rne(float f) {
    unsigned u = __float_as_uint(f);
    return (ushort)((u + 0x7fffu + ((u >> 16) & 1u)) >> 16);
}
__device__ __forceinline__ f32x2 lo2(f32x4 v) { f32x2 r; r[0] = v[0]; r[1] = v[1]; return r; }
__device__ __forceinline__ f32x2 hi2(f32x4 v) { f32x2 r; r[0] = v[2]; r[1] = v[3]; return r; }
__device__ __forceinline__ f32x2 shfl2(f32x2 v, int m) {
    f32x2 r; r[0] = __shfl_xor(v[0], m); r[1] = __shfl_xor(v[1], m); return r;
}
// quad_perm DPP: lane <- lane^1 (perm [1,0,3,2] = 0xB1), lane^2 ([2,3,0,1] = 0x4E).
// VALU pipe, not DS. All lanes active -> bound_ctrl/masks trivial.
__device__ __forceinline__ float dpp_xor1(float x) {
    return __int_as_float(__builtin_amdgcn_update_dpp(
        0, __float_as_int(x), 0xB1, 0xf, 0xf, true));
}
__device__ __forceinline__ float dpp_xor2(float x) {
    return __int_as_float(__builtin_amdgcn_update_dpp(
        0, __float_as_int(x), 0x4E, 0xf, 0xf, true));
}
__device__ __forceinline__ f32x2 dpp2_xor2(f32x2 v) {
    f32x2 r; r[0] = dpp_xor2(v[0]); r[1] = dpp_xor2(v[1]); return r;
}
// p + shfl_xor(p, 32) via v_permlane32_swap (VALU pipe, not DS).
__device__ __forceinline__ float addswap32(float p) {
    unsigned u = __float_as_uint(p);
    auto r = __builtin_amdgcn_permlane32_swap(u, u, false, false);
    return __uint_as_float(r[0]) + __uint_as_float(r[1]);
}

__global__ void prep_w(const float* __restrict__ cw, ushort* __restrict__ wp) {
    int e = blockIdx.x * 256 + threadIdx.x;   // [col=256][k=96]
    int col = e / KP, k = e - col * KP;
    float v = (k < 72) ? cw[col * 72 + k] : 0.0f;
    wp[e] = f2bf_rne(v);
}

__global__ __launch_bounds__(256, 4)
void caps_mfma2(const float* __restrict__ x,
                const ushort* __restrict__ wp,
                const float* __restrict__ bias,
                float* __restrict__ out)
{
    __shared__ ushort A[64 * LSTR];        // 13,312 B
    __shared__ float  logits[2][32 * LGS]; //  9,472 B  [px][ci][co] stride 37
    __shared__ float  routeT[2][32 * RSTR];//  9,216 B  [px][co][ci]

    const int t    = threadIdx.x;
    const int braw = blockIdx.x;                 // grid = 4096
    // XCD-ownership swizzle (bijective, 4096 = 8*512): XCD k owns batch k.
    const int bid = ((braw & 7) << 9) | (braw >> 3);
    const int b   = bid >> 9;
    const int q   = bid & 511;
    const int hw0 = q << 1;                      // even; pair = (hw0, hw0+1)
    const int h   = hw0 >> 5;
    const int w0  = hw0 & 31;                    // even, <= 30

    // ---- stage A rows: thread t <-> (row = t>>2 = px*32+ci, ni in {2qn,2qn+1})
    {
        const int row = t >> 2, qn = t & 3;
        const int px = row >> 5, ci = row & 31;
        const int wpx = w0 + px;
        const float* xb0 = x + (((size_t)((b * 32 + ci) * 8 + qn * 2)) << 10);
        const float* xb1 = xb0 + 1024;
        ushort hbuf[18];
        #pragma unroll
        for (int kh = 0; kh < 3; ++kh) {
            int hy = h + kh - 1;
            bool vh = (unsigned)hy < 32u;
            int base = hy << 5;
            #pragma unroll
            for (int c = 0; c < 3; ++c) {
                int wx = wpx + c - 1;
                bool ok = vh && ((unsigned)wx < 32u);
                float f0 = ok ? xb0[base + wx] : 0.0f;
                float f1 = ok ? xb1[base + wx] : 0.0f;
                hbuf[kh * 3 + c]     = f2bf_rne(f0);
                hbuf[9 + kh * 3 + c] = f2bf_rne(f1);
            }
        }
        // packed uint writes: shorts [row*LSTR + qn*18, +18)
        uint* Au = reinterpret_cast<uint*>(A);
        int hbase = row * (LSTR / 2) + qn * 9;
        #pragma unroll
        for (int i = 0; i < 9; ++i)
            Au[hbase + i] = (unsigned)hbuf[2 * i] | ((unsigned)hbuf[2 * i + 1] << 16);
        // zero K-pad shorts 72..103 (16 uints/row, 4 threads -> 4 each)
        int pbase = row * (LSTR / 2) + 36 + qn * 4;
        Au[pbase + 0] = 0u; Au[pbase + 1] = 0u;
        Au[pbase + 2] = 0u; Au[pbase + 3] = 0u;
    }
    __syncthreads();                     // barrier 1 (staging -> GEMM)

    const int lane = t & 63, wv = t >> 6;
    const int lc = lane & 15, grp = lane >> 4;
    const int no = lane & 7;
    const int par = (lane >> 3) & 1;

    // ---- GEMM: D[64 rows][256 cols], rows = px*32+ci. 3 k-steps of 32.
    f32x4 acc[4][4];
    #pragma unroll
    for (int mt = 0; mt < 4; ++mt)
        #pragma unroll
        for (int j = 0; j < 4; ++j) acc[mt][j] = (f32x4){0.f, 0.f, 0.f, 0.f};

    #pragma unroll
    for (int ks = 0; ks < 3; ++ks) {
        short8 bq[4];
        #pragma unroll
        for (int j = 0; j < 4; ++j) {
            int col = wv * 64 + j * 16 + lc;
            bq[j] = *reinterpret_cast<const short8*>(wp + col * KP + ks * 32 + grp * 8);
        }
        #pragma unroll
        for (int mt = 0; mt < 4; ++mt) {
            short8 af = *reinterpret_cast<const short8*>(A + (mt * 16 + lc) * LSTR + ks * 32 + grp * 8);
            #pragma unroll
            for (int j = 0; j < 4; ++j)
                acc[mt][j] = __builtin_amdgcn_mfma_f32_16x16x32_bf16(af, bq[j], acc[mt][j], 0, 0, 0);
        }
    }
    // no barrier: A is read-only from here; routing uses separate buffers

    float bj[4];
    #pragma unroll
    for (int j = 0; j < 4; ++j) bj[j] = bias[wv * 64 + j * 16 + lc];

    const int ci_s = t >> 3, j_s = t & 7;
    const int ci_w = ((no >> 2) << 4) + (grp << 2) + (no & 3);   // dist write row
    const bool b4 = (no & 4) != 0, b2 = (no & 2) != 0, b1 = (no & 1) != 0;
    float act_[2][4];

    // ================= iteration 0: route = 1/32 exactly =================
    #pragma unroll
    for (int px = 0; px < 2; ++px) {
        #pragma unroll
        for (int j = 0; j < 4; ++j) {
            f32x4 s4 = acc[px * 2][j] + acc[px * 2 + 1][j];   // 2 pk_add
            f32x2 s2v = lo2(s4) + hi2(s4);                     // 1 pk_add
            float p = s2v[0] + s2v[1];
            p += __shfl_xor(p, 16);
            p = addswap32(p);                   // sum over 32 ci (VALU swap)
            p = p * 0.03125f + bj[j];
            float s2 = p * p;
            s2 += dpp_xor1(s2);                 // VALU DPP
            s2 += dpp_xor2(s2);                 // VALU DPP
            s2 += __shfl_xor(s2, 4);            // cross-quad: DS
            act_[px][j] = p * __builtin_amdgcn_sqrtf(s2)
                            * __builtin_amdgcn_rcpf(1.0f + s2);
        }
    }
    // distances -> logits (pure write of all 1024 (ci,co) per pixel)
    #pragma unroll
    for (int px = 0; px < 2; ++px) {
        float* lg = logits[px];
        #pragma unroll
        for (int j = 0; j < 4; ++j) {
            float a = act_[px][j];
            f32x2 a2; a2[0] = a; a2[1] = a;
            f32x2 d01 = lo2(acc[px * 2][j]) * a2;       // pk_mul x4
            f32x2 d23 = hi2(acc[px * 2][j]) * a2;
            f32x2 d45 = lo2(acc[px * 2 + 1][j]) * a2;
            f32x2 d67 = hi2(acc[px * 2 + 1][j]) * a2;
            // butterfly transpose-reduce over the 8-lane no-group (packed)
            f32x2 keepA = b4 ? d45 : d01, sendA = b4 ? d01 : d45;
            f32x2 keepB = b4 ? d67 : d23, sendB = b4 ? d23 : d67;
            f32x2 eA = keepA + shfl2(sendA, 4);         // cross-quad: DS
            f32x2 eB = keepB + shfl2(sendB, 4);
            f32x2 keepC = b2 ? eB : eA, sendC = b2 ? eA : eB;
            f32x2 fC = keepC + dpp2_xor2(sendC);        // VALU DPP
            float keep = b1 ? fC[1] : fC[0];
            float send = b1 ? fC[0] : fC[1];
            float r = keep + dpp_xor1(send);            // VALU DPP
            int co = (wv << 3) + 2 * j + par;
            lg[ci_w * LGS + co] = r;
        }
    }
    __syncthreads();                     // barrier 2 (dist0 -> softmax1)

    // ================= iterations 1 and 2 =================
    for (int it = 1; it <= 2; ++it) {
        // (a) softmax over co per pixel (no max-subtract: |logits| small);
        //     store transposed routeT[co][ci]
        #pragma unroll
        for (int px = 0; px < 2; ++px) {
            const float* lg = logits[px];
            float* rt = routeT[px];
            float e0 = __expf(lg[ci_s * LGS + j_s]);
            float e1 = __expf(lg[ci_s * LGS + j_s + 8]);
            float e2 = __expf(lg[ci_s * LGS + j_s + 16]);
            float e3 = __expf(lg[ci_s * LGS + j_s + 24]);
            float s = e0 + e1 + e2 + e3;
            s += dpp_xor1(s);               // VALU DPP
            s += dpp_xor2(s);               // VALU DPP
            s += __shfl_xor(s, 4);          // cross-quad: DS
            float inv = __builtin_amdgcn_rcpf(s);
            rt[(j_s)      * RSTR + ci_s] = e0 * inv;
            rt[(j_s + 8)  * RSTR + ci_s] = e1 * inv;
            rt[(j_s + 16) * RSTR + ci_s] = e2 * inv;
            rt[(j_s + 24) * RSTR + ci_s] = e3 * inv;
        }
        __syncthreads();                 // barrier 3 / 5 (routeT -> preact)

        // (b) preactivate (packed dot, ci-reduce xor16 + permlane32) + squash
        #pragma unroll
        for (int px = 0; px < 2; ++px) {
            const float* rt = routeT[px];
            #pragma unroll
            for (int j = 0; j < 4; ++j) {
                int co = (wv << 3) + 2 * j + par;
                f32x4 r0 = *reinterpret_cast<const f32x4*>(rt + co * RSTR + grp * 4);
                f32x4 r1 = *reinterpret_cast<const f32x4*>(rt + co * RSTR + 16 + grp * 4);
                f32x2 pp = lo2(r0) * lo2(acc[px * 2][j]);          // pk_mul
                pp = hi2(r0) * hi2(acc[px * 2][j]) + pp;           // pk_fma
                pp = lo2(r1) * lo2(acc[px * 2 + 1][j]) + pp;
                pp = hi2(r1) * hi2(acc[px * 2 + 1][j]) + pp;
                float p = pp[0] + pp[1];
                p += __shfl_xor(p, 16);
                p = addswap32(p);               // VALU swap, not DS
                p += bj[j];
                float s2 = p * p;
                s2 += dpp_xor1(s2);             // VALU DPP
                s2 += dpp_xor2(s2);             // VALU DPP
                s2 += __shfl_xor(s2, 4);        // cross-quad: DS
                act_[px][j] = p * __builtin_amdgcn_sqrtf(s2)
                                * __builtin_amdgcn_rcpf(1.0f + s2);
            }
        }
        if (it == 2) break;

        // (c) distances += (packed butterfly), accumulate into logits
        #pragma unroll
        for (int px = 0; px < 2; ++px) {
            float* lg = logits[px];
            #pragma unroll
            for (int j = 0; j < 4; ++j) {
                float a = act_[px][j];
                f32x2 a2; a2[0] = a; a2[1] = a;
                f32x2 d01 = lo2(acc[px * 2][j]) * a2;
                f32x2 d23 = hi2(acc[px * 2][j]) * a2;
                f32x2 d45 = lo2(acc[px * 2 + 1][j]) * a2;
                f32x2 d67 = hi2(acc[px * 2 + 1][j]) * a2;
                f32x2 keepA = b4 ? d45 : d01, sendA = b4 ? d01 : d45;
                f32x2 keepB = b4 ? d67 : d23, sendB = b4 ? d23 : d67;
                f32x2 eA = keepA + shfl2(sendA, 4);     // DS
                f32x2 eB = keepB + shfl2(sendB, 4);
                f32x2 keepC = b2 ? eB : eA, sendC = b2 ? eA : eB;
                f32x2 fC = keepC + dpp2_xor2(sendC);    // VALU DPP
                float keep = b1 ? fC[1] : fC[0];
                float send = b1 ? fC[0] : fC[1];
                float r = keep + dpp_xor1(send);        // VALU DPP
                int co = (wv << 3) + 2 * j + par;
                lg[ci_w * LGS + co] += r;
            }
        }
        __syncthreads();                 // barrier 4 (dist1 -> softmax2)
    }

    // ---- output: grp 0 writes the wave's 64 cols, both pixels as float2
    if (grp == 0) {
        #pragma unroll
        for (int j = 0; j < 4; ++j) {
            int col = wv * 64 + j * 16 + lc;
            float2 v; v.x = act_[0][j]; v.y = act_[1][j];
            *reinterpret_cast<float2*>(out + ((((size_t)b << 8) + col) << 10) + hw0) = v;
        }
    }
}

extern "C" void kernel_launch(void* const* d_in, const int* in_sizes, int n_in,
                              void* d_out, int out_size, void* d_ws, size_t ws_size,
                              hipStream_t stream) {
    const float* x    = (const float*)d_in[0];
    const float* cw   = (const float*)d_in[1];
    const float* bias = (const float*)d_in[2];
    float* out = (float*)d_out;
    ushort* wp = (ushort*)d_ws;           // 256*96*2 = 49,152 B
    (void)in_sizes; (void)n_in; (void)out_size; (void)ws_size;
    prep_w<<<96, 256, 0, stream>>>(cw, wp);
    caps_mfma2<<<4096, 256, 0, stream>>>(x, wp, bias, out);
}